// Round 16
// baseline (235.886 us; speedup 1.0000x reference)
//
#include <hip/hip_runtime.h>

#define N_NODES 50000
#define N_EDGES 800000
#define DIM 256
#define NB 196        // ceil(N_NODES/256)
#define UNROLL 8      // ELL pad quantum
#define MAXE (N_EDGES + N_NODES * UNROLL)  // padded edge capacity = 1.2M
#define CSB 512       // colsum stage-1 blocks
#define NCH 4         // feature chunks
#define CCOLS 64      // cols per chunk
#define CHSZ (N_NODES * CCOLS)  // ushorts per chunk region (6.4 MB)
#define RPB 8         // rows per block in aggc (4 waves x 2 rows)
#define CHB (N_NODES / RPB)     // 6250 row-blocks per chunk

typedef __attribute__((ext_vector_type(8))) short bf16x8;
typedef __attribute__((ext_vector_type(4))) float f32x4;
typedef __attribute__((ext_vector_type(2))) float f32x2;

// ---- bf16 helpers (RNE) ----
__device__ __forceinline__ unsigned int f2bf(float f) {
  unsigned int u = __float_as_uint(f);
  return (u + 0x7FFFu + ((u >> 16) & 1u)) >> 16;  // low 16 bits valid
}
__device__ __forceinline__ float bf_lo(unsigned int u) {
  return __uint_as_float(u << 16);
}
__device__ __forceinline__ float bf_hi(unsigned int u) {
  return __uint_as_float(u & 0xFFFF0000u);
}

// ---------------- CSR build (ELL-padded to UNROLL), round-9 proven chain ----------------

__global__ void k_deg(const int* __restrict__ dst, int* __restrict__ deg) {
  int e = blockIdx.x * blockDim.x + threadIdx.x;
  if (e < N_EDGES) atomicAdd(&deg[dst[e]], 1);
}

// per-256-chunk PADDED degree sums + dinv
__global__ __launch_bounds__(256) void k_bsum(const int* __restrict__ deg,
                                              float* __restrict__ dinv,
                                              int* __restrict__ bsum) {
  __shared__ int red[4];
  const int t = threadIdx.x;
  const int i = blockIdx.x * 256 + t;
  int pd = 0;
  if (i < N_NODES) {
    int d = deg[i];
    dinv[i] = rsqrtf((float)(d + 1));  // +1 self-loop
    pd = (d + UNROLL - 1) & ~(UNROLL - 1);
  }
  int s = pd;
#pragma unroll
  for (int off = 32; off > 0; off >>= 1) s += __shfl_down(s, off);
  if ((t & 63) == 0) red[t >> 6] = s;
  __syncthreads();
  if (t == 0) bsum[blockIdx.x] = red[0] + red[1] + red[2] + red[3];
}

__global__ __launch_bounds__(256) void k_bscan(const int* __restrict__ bsum,
                                               int* __restrict__ boff,
                                               int* __restrict__ row_start) {
  __shared__ int s[256];
  const int t = threadIdx.x;
  int v = (t < NB) ? bsum[t] : 0;
  s[t] = v;
  __syncthreads();
  for (int off = 1; off < 256; off <<= 1) {
    int u = (t >= off) ? s[t - off] : 0;
    __syncthreads();
    s[t] += u;
    __syncthreads();
  }
  if (t < NB) boff[t] = s[t] - v;
  if (t == NB - 1) row_start[N_NODES] = s[NB - 1];  // total padded length
}

__global__ __launch_bounds__(256) void k_rowstart(const int* __restrict__ deg,
                                                  const int* __restrict__ boff,
                                                  int* __restrict__ row_start,
                                                  int* __restrict__ cursor) {
  __shared__ int s[256];
  const int t = threadIdx.x;
  const int i = blockIdx.x * 256 + t;
  int pd = (i < N_NODES) ? ((deg[i] + UNROLL - 1) & ~(UNROLL - 1)) : 0;
  s[t] = pd;
  __syncthreads();
  for (int off = 1; off < 256; off <<= 1) {
    int u = (t >= off) ? s[t - off] : 0;
    __syncthreads();
    s[t] += u;
    __syncthreads();
  }
  if (i < N_NODES) {
    int r = boff[blockIdx.x] + s[t] - pd;
    row_start[i] = r;
    cursor[i] = r;
  }
}

// scatter combined meta: {src | perm[src]<<16, norm(f32)}. Pad slots stay
// {0, 0.0f} from memset -> gather row 0 (cache-hot) with weight 0.
__global__ void k_scatter(const int* __restrict__ src, const int* __restrict__ dst,
                          const int* __restrict__ perm, const float* __restrict__ dinv,
                          int* __restrict__ cursor, uint2* __restrict__ meta) {
  int e = blockIdx.x * blockDim.x + threadIdx.x;
  if (e < N_EDGES) {
    int s = src[e], d = dst[e];
    int p = atomicAdd(&cursor[d], 1);
    meta[p] = make_uint2((unsigned)s | ((unsigned)perm[s] << 16),
                         __float_as_uint(dinv[s] * dinv[d]));
  }
}

// ---------------- W transpose + bf16 convert: Wt[n][k] ----------------

__global__ void k_prep(const float* __restrict__ W, ushort* __restrict__ Wt) {
  int n = blockIdx.x, k = threadIdx.x;
  Wt[n * DIM + k] = (ushort)f2bf(W[k * DIM + n]);
}

// ---------------- GEMM: XW = X @ W (bf16 MFMA, out chunk-major bf16) ----------------
// BM=128, BN=256, BK=32, 512 threads (8 waves, 2m x 4n) — round-9 proven config.

__global__ __launch_bounds__(512) void k_gemm(const float* __restrict__ X,
                                              const ushort* __restrict__ Wt,
                                              ushort* __restrict__ XWC) {
  __shared__ ushort Xs[128 * 40];
  __shared__ ushort Ws[256 * 40];
  const int tid = threadIdx.x;
  const int lane = tid & 63;
  const int w = tid >> 6;
  const int wm = w >> 2, wn = w & 3;
  const int m0 = blockIdx.x * 128;
  const int l16 = lane & 15, kh = lane >> 4;

  f32x4 acc[4][4];
#pragma unroll
  for (int mf = 0; mf < 4; ++mf)
#pragma unroll
    for (int nf = 0; nf < 4; ++nf) acc[mf][nf] = (f32x4){0.f, 0.f, 0.f, 0.f};

  for (int k0 = 0; k0 < DIM; k0 += 32) {
#pragma unroll
    for (int it = 0; it < 2; ++it) {
      int idx = tid + it * 512;
      int row = idx >> 3, q = idx & 7;
      int grow = m0 + row;
      float4 v = make_float4(0.f, 0.f, 0.f, 0.f);
      if (grow < N_NODES)
        v = *reinterpret_cast<const float4*>(&X[(size_t)grow * DIM + k0 + q * 4]);
      uint2 p;
      p.x = f2bf(v.x) | (f2bf(v.y) << 16);
      p.y = f2bf(v.z) | (f2bf(v.w) << 16);
      *reinterpret_cast<uint2*>(&Xs[row * 40 + q * 4]) = p;
    }
#pragma unroll
    for (int it = 0; it < 2; ++it) {
      int idx = tid + it * 512;
      int n = idx >> 2, c = idx & 3;
      uint4 wv = *reinterpret_cast<const uint4*>(&Wt[n * DIM + k0 + c * 8]);
      *reinterpret_cast<uint4*>(&Ws[n * 40 + c * 8]) = wv;
    }
    __syncthreads();
    bf16x8 a[4], b[4];
#pragma unroll
    for (int f = 0; f < 4; ++f) {
      a[f] = *reinterpret_cast<const bf16x8*>(&Ws[(wn * 64 + f * 16 + l16) * 40 + kh * 8]);
      b[f] = *reinterpret_cast<const bf16x8*>(&Xs[(wm * 64 + f * 16 + l16) * 40 + kh * 8]);
    }
#pragma unroll
    for (int mf = 0; mf < 4; ++mf)
#pragma unroll
      for (int nf = 0; nf < 4; ++nf)
        acc[mf][nf] = __builtin_amdgcn_mfma_f32_16x16x32_bf16(a[nf], b[mf],
                                                              acc[mf][nf], 0, 0, 0);
    __syncthreads();
  }
#pragma unroll
  for (int mf = 0; mf < 4; ++mf) {
    int m = m0 + wm * 64 + mf * 16 + l16;
    if (m >= N_NODES) continue;
#pragma unroll
    for (int nf = 0; nf < 4; ++nf) {
      int nb = wn * 64 + nf * 16 + kh * 4;  // global col, 4-aligned
      uint2 p;
      p.x = f2bf(acc[mf][nf][0]) | (f2bf(acc[mf][nf][1]) << 16);
      p.y = f2bf(acc[mf][nf][2]) | (f2bf(acc[mf][nf][3]) << 16);
      // chunk-major: [chunk][node][CCOLS]
      *reinterpret_cast<uint2*>(
          &XWC[(size_t)(nb >> 6) * CHSZ + (size_t)m * CCOLS + (nb & 63)]) = p;
    }
  }
}

// ---------------- fused dual aggregation, chunked, pk-f32, fast unpack ----------------

// Fast bf16-pair unpack: lo = u<<16 (exact), hi = u raw (low 16 mantissa bits
// garbage, <=2^-7 relative) — verified absmax unchanged at 0.03125.
__device__ __forceinline__ void fma8v(f32x2* A, uint4 v, f32x2 n) {
  A[0] += (f32x2){__uint_as_float(v.x << 16), __uint_as_float(v.x)} * n;
  A[1] += (f32x2){__uint_as_float(v.y << 16), __uint_as_float(v.y)} * n;
  A[2] += (f32x2){__uint_as_float(v.z << 16), __uint_as_float(v.z)} * n;
  A[3] += (f32x2){__uint_as_float(v.w << 16), __uint_as_float(v.w)} * n;
}

// 32 lanes per row (2 rows/wave — halves degree-divergence waste vs 4 rows):
// eg = edge group (0..3), sc = 16B col slice (0..7). 8 edges/iter per row,
// 4 gathers in flight/lane; next-iter meta prefetched before the FMA block.
__global__ __launch_bounds__(256) void k_aggc(
    const ushort* __restrict__ xwc, const int* __restrict__ row_start,
    const uint2* __restrict__ meta, const int* __restrict__ perm,
    const float* __restrict__ dinv, const float* __restrict__ bias,
    const float* __restrict__ slope, ushort* __restrict__ z1,
    ushort* __restrict__ z2) {
  const int blk = blockIdx.x;
  const int ch = blk / CHB;        // chunk phase (x-ordered dispatch)
  const int rb = blk % CHB;
  const int tid = threadIdx.x;
  const int r = rb * RPB + (tid >> 5);   // 8 rows/block, 2 per wave
  const int l = tid & 31;
  const int eg = l >> 3;           // 0..3
  const int sc = l & 7;            // 0..7 (8 cols each)
  const ushort* xcs = xwc + (size_t)ch * CHSZ + sc * 8;  // col-slice base
  const uint2* mp = meta + eg * 2; // per-lane meta base

  f32x2 a1[4] = {{0.f, 0.f}, {0.f, 0.f}, {0.f, 0.f}, {0.f, 0.f}};
  f32x2 a2[4] = {{0.f, 0.f}, {0.f, 0.f}, {0.f, 0.f}, {0.f, 0.f}};
  int e = row_start[r];
  const int eEnd = row_start[r + 1];
  if (e < eEnd) {
    uint4 m0 = *reinterpret_cast<const uint4*>(mp + e);
    while (e < eEnd) {
      // 2 edges (A,B) x 2 streams for this lane's eg slot
      uint4 vA1 = *reinterpret_cast<const uint4*>(xcs + ((m0.x & 0xFFFFu) << 6));
      uint4 vA2 = *reinterpret_cast<const uint4*>(xcs + ((m0.x >> 16) << 6));
      uint4 vB1 = *reinterpret_cast<const uint4*>(xcs + ((m0.z & 0xFFFFu) << 6));
      uint4 vB2 = *reinterpret_cast<const uint4*>(xcs + ((m0.z >> 16) << 6));
      const int en = e + 8;
      const int ep = (en < eEnd) ? en : e;
      uint4 m0n = *reinterpret_cast<const uint4*>(mp + ep);  // prefetch next
      const float fA = __uint_as_float(m0.y), fB = __uint_as_float(m0.w);
      const f32x2 nA = {fA, fA}, nB = {fB, fB};
      fma8v(a1, vA1, nA); fma8v(a2, vA2, nA);
      fma8v(a1, vB1, nB); fma8v(a2, vB2, nB);
      m0 = m0n;
      e = en;
    }
  }
  // reduce the eg dimension (partners within the 32-lane row group)
#pragma unroll
  for (int j = 0; j < 4; ++j) {
    a1[j].x += __shfl_xor(a1[j].x, 8);
    a1[j].y += __shfl_xor(a1[j].y, 8);
    a2[j].x += __shfl_xor(a2[j].x, 8);
    a2[j].y += __shfl_xor(a2[j].y, 8);
    a1[j].x += __shfl_xor(a1[j].x, 16);
    a1[j].y += __shfl_xor(a1[j].y, 16);
    a2[j].x += __shfl_xor(a2[j].x, 16);
    a2[j].y += __shfl_xor(a2[j].y, 16);
  }
  if (eg == 0) {
    const float di = dinv[r];
    const float d2 = di * di;
    const f32x2 nd = {d2, d2};
    const int pr = perm[r];
    uint4 s1 = *reinterpret_cast<const uint4*>(xcs + ((unsigned)r << 6));
    uint4 s2 = *reinterpret_cast<const uint4*>(xcs + ((unsigned)pr << 6));
    fma8v(a1, s1, nd); fma8v(a2, s2, nd);
    const float* bp = bias + ch * CCOLS + sc * 8;
    float4 b0 = *reinterpret_cast<const float4*>(bp);
    float4 b1 = *reinterpret_cast<const float4*>(bp + 4);
    a1[0] += (f32x2){b0.x, b0.y}; a1[1] += (f32x2){b0.z, b0.w};
    a1[2] += (f32x2){b1.x, b1.y}; a1[3] += (f32x2){b1.z, b1.w};
    a2[0] += (f32x2){b0.x, b0.y}; a2[1] += (f32x2){b0.z, b0.w};
    a2[2] += (f32x2){b1.x, b1.y}; a2[3] += (f32x2){b1.z, b1.w};
    const float a0 = slope[0];
#pragma unroll
    for (int j = 0; j < 4; ++j) {
      a1[j].x = a1[j].x >= 0.f ? a1[j].x : a0 * a1[j].x;
      a1[j].y = a1[j].y >= 0.f ? a1[j].y : a0 * a1[j].y;
      a2[j].x = a2[j].x >= 0.f ? a2[j].x : a0 * a2[j].x;
      a2[j].y = a2[j].y >= 0.f ? a2[j].y : a0 * a2[j].y;
    }
    uint4 p1, p2;
    p1.x = f2bf(a1[0].x) | (f2bf(a1[0].y) << 16);
    p1.y = f2bf(a1[1].x) | (f2bf(a1[1].y) << 16);
    p1.z = f2bf(a1[2].x) | (f2bf(a1[2].y) << 16);
    p1.w = f2bf(a1[3].x) | (f2bf(a1[3].y) << 16);
    p2.x = f2bf(a2[0].x) | (f2bf(a2[0].y) << 16);
    p2.y = f2bf(a2[1].x) | (f2bf(a2[1].y) << 16);
    p2.z = f2bf(a2[2].x) | (f2bf(a2[2].y) << 16);
    p2.w = f2bf(a2[3].x) | (f2bf(a2[3].y) << 16);
    const size_t o = (size_t)r * DIM + ch * CCOLS + sc * 8;  // z row-major
    *reinterpret_cast<uint4*>(z1 + o) = p1;
    *reinterpret_cast<uint4*>(z2 + o) = p2;
  }
}

// ---------------- column sums (2-stage, no atomics, CSB=512) ----------------

__global__ __launch_bounds__(256) void k_colsum(const ushort* __restrict__ z1,
                                                float* __restrict__ partial) {
  __shared__ float red[8 * 256];
  const int t = threadIdx.x;
  const int c8 = t & 31;       // col block of 8
  const int g = t >> 5;        // row group 0..7
  float s[8] = {0.f, 0.f, 0.f, 0.f, 0.f, 0.f, 0.f, 0.f};
  for (int r = blockIdx.x * 8 + g; r < N_NODES; r += 8 * CSB) {
    uint4 v = *reinterpret_cast<const uint4*>(z1 + (size_t)r * DIM + c8 * 8);
    s[0] += bf_lo(v.x); s[1] += bf_hi(v.x);
    s[2] += bf_lo(v.y); s[3] += bf_hi(v.y);
    s[4] += bf_lo(v.z); s[5] += bf_hi(v.z);
    s[6] += bf_lo(v.w); s[7] += bf_hi(v.w);
  }
#pragma unroll
  for (int j = 0; j < 8; ++j) red[g * 256 + c8 * 8 + j] = s[j];
  __syncthreads();
  float tot = 0.f;
#pragma unroll
  for (int g2 = 0; g2 < 8; ++g2) tot += red[g2 * 256 + t];
  partial[blockIdx.x * 256 + t] = tot;  // coalesced, no atomics
}

// reduce partials + sigmoid + wsum = disc_W @ summary, one block
__global__ __launch_bounds__(256) void k_wsum(const float* __restrict__ partial,
                                              const float* __restrict__ disc_W,
                                              float* __restrict__ wsum) {
  __shared__ float s[DIM];
  const int t = threadIdx.x;
  float a0 = 0.f, a1 = 0.f, a2 = 0.f, a3 = 0.f;
  for (int b = 0; b < CSB; b += 4) {
    a0 += partial[(b + 0) * 256 + t];
    a1 += partial[(b + 1) * 256 + t];
    a2 += partial[(b + 2) * 256 + t];
    a3 += partial[(b + 3) * 256 + t];
  }
  float m = (a0 + a1 + a2 + a3) * (1.0f / (float)N_NODES);
  s[t] = 1.0f / (1.0f + expf(-m));
  __syncthreads();
  float acc = 0.f;
  for (int j = 0; j < DIM; j += 4) {
    float4 w4 = *reinterpret_cast<const float4*>(&disc_W[t * DIM + j]);
    acc += w4.x * s[j] + w4.y * s[j + 1] + w4.z * s[j + 2] + w4.w * s[j + 3];
  }
  wsum[t] = acc;
}

// ---------------- pos = z1 @ wsum, neg = z2 @ wsum (wave per row) ----------------

__global__ __launch_bounds__(256) void k_posneg(const ushort* __restrict__ z1,
                                                const ushort* __restrict__ z2,
                                                const float* __restrict__ wsum,
                                                float* __restrict__ pos,
                                                float* __restrict__ neg) {
  const int wid = (blockIdx.x * blockDim.x + threadIdx.x) >> 6;
  const int lane = threadIdx.x & 63;
  if (wid >= N_NODES) return;
  uint2 v1 = *reinterpret_cast<const uint2*>(z1 + (size_t)wid * DIM + lane * 4);
  uint2 v2 = *reinterpret_cast<const uint2*>(z2 + (size_t)wid * DIM + lane * 4);
  float4 w4 = *reinterpret_cast<const float4*>(&wsum[lane * 4]);
  float dp = bf_lo(v1.x) * w4.x + bf_hi(v1.x) * w4.y + bf_lo(v1.y) * w4.z + bf_hi(v1.y) * w4.w;
  float dn = bf_lo(v2.x) * w4.x + bf_hi(v2.x) * w4.y + bf_lo(v2.y) * w4.z + bf_hi(v2.y) * w4.w;
#pragma unroll
  for (int off = 32; off > 0; off >>= 1) {
    dp += __shfl_down(dp, off);
    dn += __shfl_down(dn, off);
  }
  if (lane == 0) { pos[wid] = dp; neg[wid] = dn; }
}

// ---------------- launch ----------------

extern "C" void kernel_launch(void* const* d_in, const int* in_sizes, int n_in,
                              void* d_out, int out_size, void* d_ws, size_t ws_size,
                              hipStream_t stream) {
  const float* x      = (const float*)d_in[0];
  const float* W      = (const float*)d_in[1];
  const float* b      = (const float*)d_in[2];
  const float* a      = (const float*)d_in[3];
  const float* disc_W = (const float*)d_in[4];
  const int*   eidx   = (const int*)d_in[5];
  const int*   perm   = (const int*)d_in[6];
  const int* src = eidx;
  const int* dst = eidx + N_EDGES;

  constexpr size_t SZ_BFM  = (size_t)N_NODES * DIM * 2;  // 25.6 MB
  constexpr size_t SZ_META = (size_t)MAXE * 8;           // 9.6 MB
  constexpr size_t OFF_XWC = 0;
  constexpr size_t OFF_Z1  = OFF_XWC + SZ_BFM;
  constexpr size_t OFF_Z2  = OFF_Z1 + SZ_BFM;
  constexpr size_t OFF_WT  = OFF_Z2 + SZ_BFM;
  constexpr size_t OFF_DEG = OFF_WT + 131072;
  constexpr size_t OFF_DNV = OFF_DEG + 200192;
  constexpr size_t OFF_RS  = OFF_DNV + 200192;  // row_start: N+1 ints
  constexpr size_t OFF_CUR = OFF_RS + 200448;
  constexpr size_t OFF_MT  = OFF_CUR + 200192;
  constexpr size_t OFF_WSM = OFF_MT + SZ_META;
  constexpr size_t OFF_BS  = OFF_WSM + 1024;
  constexpr size_t OFF_BO  = OFF_BS + 1024;
  constexpr size_t OFF_PT  = OFF_BO + 1024;
  constexpr size_t NEED    = OFF_PT + (size_t)CSB * 256 * 4;
  if (ws_size < NEED) return;

  char* ws = (char*)d_ws;
  ushort* xwc    = (ushort*)(ws + OFF_XWC);
  ushort* z1     = (ushort*)(ws + OFF_Z1);
  ushort* z2     = (ushort*)(ws + OFF_Z2);
  ushort* Wt     = (ushort*)(ws + OFF_WT);
  int*    deg    = (int*)(ws + OFF_DEG);
  float*  dinv   = (float*)(ws + OFF_DNV);
  int*    rowst  = (int*)(ws + OFF_RS);
  int*    cursor = (int*)(ws + OFF_CUR);
  uint2*  meta   = (uint2*)(ws + OFF_MT);
  float*  wsum   = (float*)(ws + OFF_WSM);
  int*    bsum   = (int*)(ws + OFF_BS);
  int*    boff   = (int*)(ws + OFF_BO);
  float*  partial= (float*)(ws + OFF_PT);

  float* pos = (float*)d_out;
  float* neg = pos + N_NODES;

  hipMemsetAsync(deg, 0, N_NODES * sizeof(int), stream);
  hipMemsetAsync(meta, 0, SZ_META, stream);  // pad slots -> {src 0, psrc 0, norm 0}

  k_deg<<<(N_EDGES + 255) / 256, 256, 0, stream>>>(dst, deg);
  k_bsum<<<NB, 256, 0, stream>>>(deg, dinv, bsum);
  k_bscan<<<1, 256, 0, stream>>>(bsum, boff, rowst);
  k_rowstart<<<NB, 256, 0, stream>>>(deg, boff, rowst, cursor);
  k_scatter<<<(N_EDGES + 255) / 256, 256, 0, stream>>>(src, dst, perm, dinv,
                                                       cursor, meta);

  k_prep<<<DIM, DIM, 0, stream>>>(W, Wt);
  k_gemm<<<(N_NODES + 127) / 128, 512, 0, stream>>>(x, Wt, xwc);

  // fused dual aggregation: 4 chunk phases x 6250 row-blocks (x-ordered)
  k_aggc<<<NCH * CHB, 256, 0, stream>>>(xwc, rowst, meta, perm, dinv, b, a, z1, z2);

  k_colsum<<<CSB, 256, 0, stream>>>(z1, partial);
  k_wsum<<<1, 256, 0, stream>>>(partial, disc_W, wsum);
  k_posneg<<<(N_NODES * 64 + 255) / 256, 256, 0, stream>>>(z1, z2, wsum, pos, neg);
}

// Round 17
// 232.774 us; speedup vs baseline: 1.0134x; 1.0134x over previous
//
#include <hip/hip_runtime.h>

#define N_NODES 50000
#define N_EDGES 800000
#define DIM 256
#define NB 196        // ceil(N_NODES/256)
#define UNROLL 8      // ELL pad quantum
#define MAXE (N_EDGES + N_NODES * UNROLL)  // padded edge capacity = 1.2M
#define CSB 512       // colsum stage-1 blocks
#define NCH 4         // feature chunks
#define CCOLS 64      // cols per chunk
#define CHSZ (N_NODES * CCOLS)  // ushorts per chunk region (6.4 MB)
#define RPB 16        // rows per block in aggc
#define CHB (N_NODES / RPB)     // 3125 row-blocks per chunk

typedef __attribute__((ext_vector_type(8))) short bf16x8;
typedef __attribute__((ext_vector_type(4))) float f32x4;
typedef __attribute__((ext_vector_type(2))) float f32x2;

// ---- bf16 helpers (RNE) ----
__device__ __forceinline__ unsigned int f2bf(float f) {
  unsigned int u = __float_as_uint(f);
  return (u + 0x7FFFu + ((u >> 16) & 1u)) >> 16;  // low 16 bits valid
}
__device__ __forceinline__ float bf_lo(unsigned int u) {
  return __uint_as_float(u << 16);
}
__device__ __forceinline__ float bf_hi(unsigned int u) {
  return __uint_as_float(u & 0xFFFF0000u);
}

// ---------------- CSR build (ELL-padded to UNROLL), round-9 proven chain ----------------

__global__ void k_deg(const int* __restrict__ dst, int* __restrict__ deg) {
  int e = blockIdx.x * blockDim.x + threadIdx.x;
  if (e < N_EDGES) atomicAdd(&deg[dst[e]], 1);
}

// per-256-chunk PADDED degree sums + dinv
__global__ __launch_bounds__(256) void k_bsum(const int* __restrict__ deg,
                                              float* __restrict__ dinv,
                                              int* __restrict__ bsum) {
  __shared__ int red[4];
  const int t = threadIdx.x;
  const int i = blockIdx.x * 256 + t;
  int pd = 0;
  if (i < N_NODES) {
    int d = deg[i];
    dinv[i] = rsqrtf((float)(d + 1));  // +1 self-loop
    pd = (d + UNROLL - 1) & ~(UNROLL - 1);
  }
  int s = pd;
#pragma unroll
  for (int off = 32; off > 0; off >>= 1) s += __shfl_down(s, off);
  if ((t & 63) == 0) red[t >> 6] = s;
  __syncthreads();
  if (t == 0) bsum[blockIdx.x] = red[0] + red[1] + red[2] + red[3];
}

__global__ __launch_bounds__(256) void k_bscan(const int* __restrict__ bsum,
                                               int* __restrict__ boff,
                                               int* __restrict__ row_start) {
  __shared__ int s[256];
  const int t = threadIdx.x;
  int v = (t < NB) ? bsum[t] : 0;
  s[t] = v;
  __syncthreads();
  for (int off = 1; off < 256; off <<= 1) {
    int u = (t >= off) ? s[t - off] : 0;
    __syncthreads();
    s[t] += u;
    __syncthreads();
  }
  if (t < NB) boff[t] = s[t] - v;
  if (t == NB - 1) row_start[N_NODES] = s[NB - 1];  // total padded length
}

__global__ __launch_bounds__(256) void k_rowstart(const int* __restrict__ deg,
                                                  const int* __restrict__ boff,
                                                  int* __restrict__ row_start,
                                                  int* __restrict__ cursor) {
  __shared__ int s[256];
  const int t = threadIdx.x;
  const int i = blockIdx.x * 256 + t;
  int pd = (i < N_NODES) ? ((deg[i] + UNROLL - 1) & ~(UNROLL - 1)) : 0;
  s[t] = pd;
  __syncthreads();
  for (int off = 1; off < 256; off <<= 1) {
    int u = (t >= off) ? s[t - off] : 0;
    __syncthreads();
    s[t] += u;
    __syncthreads();
  }
  if (i < N_NODES) {
    int r = boff[blockIdx.x] + s[t] - pd;
    row_start[i] = r;
    cursor[i] = r;
  }
}

// scatter combined meta: {src | perm[src]<<16, norm(f32)}. Pad slots stay
// {0, 0.0f} from memset -> gather row 0 (cache-hot) with weight 0.
__global__ void k_scatter(const int* __restrict__ src, const int* __restrict__ dst,
                          const int* __restrict__ perm, const float* __restrict__ dinv,
                          int* __restrict__ cursor, uint2* __restrict__ meta) {
  int e = blockIdx.x * blockDim.x + threadIdx.x;
  if (e < N_EDGES) {
    int s = src[e], d = dst[e];
    int p = atomicAdd(&cursor[d], 1);
    meta[p] = make_uint2((unsigned)s | ((unsigned)perm[s] << 16),
                         __float_as_uint(dinv[s] * dinv[d]));
  }
}

// ---------------- W transpose + bf16 convert: Wt[n][k] ----------------

__global__ void k_prep(const float* __restrict__ W, ushort* __restrict__ Wt) {
  int n = blockIdx.x, k = threadIdx.x;
  Wt[n * DIM + k] = (ushort)f2bf(W[k * DIM + n]);
}

// ---------------- GEMM: XW = X @ W (bf16 MFMA, out chunk-major bf16) ----------------
// BM=128, BN=256, BK=32, 512 threads (8 waves, 2m x 4n) — round-9 proven config.

__global__ __launch_bounds__(512) void k_gemm(const float* __restrict__ X,
                                              const ushort* __restrict__ Wt,
                                              ushort* __restrict__ XWC) {
  __shared__ ushort Xs[128 * 40];
  __shared__ ushort Ws[256 * 40];
  const int tid = threadIdx.x;
  const int lane = tid & 63;
  const int w = tid >> 6;
  const int wm = w >> 2, wn = w & 3;
  const int m0 = blockIdx.x * 128;
  const int l16 = lane & 15, kh = lane >> 4;

  f32x4 acc[4][4];
#pragma unroll
  for (int mf = 0; mf < 4; ++mf)
#pragma unroll
    for (int nf = 0; nf < 4; ++nf) acc[mf][nf] = (f32x4){0.f, 0.f, 0.f, 0.f};

  for (int k0 = 0; k0 < DIM; k0 += 32) {
#pragma unroll
    for (int it = 0; it < 2; ++it) {
      int idx = tid + it * 512;
      int row = idx >> 3, q = idx & 7;
      int grow = m0 + row;
      float4 v = make_float4(0.f, 0.f, 0.f, 0.f);
      if (grow < N_NODES)
        v = *reinterpret_cast<const float4*>(&X[(size_t)grow * DIM + k0 + q * 4]);
      uint2 p;
      p.x = f2bf(v.x) | (f2bf(v.y) << 16);
      p.y = f2bf(v.z) | (f2bf(v.w) << 16);
      *reinterpret_cast<uint2*>(&Xs[row * 40 + q * 4]) = p;
    }
#pragma unroll
    for (int it = 0; it < 2; ++it) {
      int idx = tid + it * 512;
      int n = idx >> 2, c = idx & 3;
      uint4 wv = *reinterpret_cast<const uint4*>(&Wt[n * DIM + k0 + c * 8]);
      *reinterpret_cast<uint4*>(&Ws[n * 40 + c * 8]) = wv;
    }
    __syncthreads();
    bf16x8 a[4], b[4];
#pragma unroll
    for (int f = 0; f < 4; ++f) {
      a[f] = *reinterpret_cast<const bf16x8*>(&Ws[(wn * 64 + f * 16 + l16) * 40 + kh * 8]);
      b[f] = *reinterpret_cast<const bf16x8*>(&Xs[(wm * 64 + f * 16 + l16) * 40 + kh * 8]);
    }
#pragma unroll
    for (int mf = 0; mf < 4; ++mf)
#pragma unroll
      for (int nf = 0; nf < 4; ++nf)
        acc[mf][nf] = __builtin_amdgcn_mfma_f32_16x16x32_bf16(a[nf], b[mf],
                                                              acc[mf][nf], 0, 0, 0);
    __syncthreads();
  }
#pragma unroll
  for (int mf = 0; mf < 4; ++mf) {
    int m = m0 + wm * 64 + mf * 16 + l16;
    if (m >= N_NODES) continue;
#pragma unroll
    for (int nf = 0; nf < 4; ++nf) {
      int nb = wn * 64 + nf * 16 + kh * 4;  // global col, 4-aligned
      uint2 p;
      p.x = f2bf(acc[mf][nf][0]) | (f2bf(acc[mf][nf][1]) << 16);
      p.y = f2bf(acc[mf][nf][2]) | (f2bf(acc[mf][nf][3]) << 16);
      // chunk-major: [chunk][node][CCOLS]
      *reinterpret_cast<uint2*>(
          &XWC[(size_t)(nb >> 6) * CHSZ + (size_t)m * CCOLS + (nb & 63)]) = p;
    }
  }
}

// ---------------- fused dual aggregation, chunked, pk-f32, fast unpack ----------------

// Fast bf16-pair unpack: lo = u<<16 (exact), hi = u raw (low 16 mantissa bits
// garbage, <=2^-7 relative) — verified absmax unchanged at 0.03125.
__device__ __forceinline__ void fma8v(f32x2* A, uint4 v, f32x2 n) {
  A[0] += (f32x2){__uint_as_float(v.x << 16), __uint_as_float(v.x)} * n;
  A[1] += (f32x2){__uint_as_float(v.y << 16), __uint_as_float(v.y)} * n;
  A[2] += (f32x2){__uint_as_float(v.z << 16), __uint_as_float(v.z)} * n;
  A[3] += (f32x2){__uint_as_float(v.w << 16), __uint_as_float(v.w)} * n;
}

// 16 lanes per row: eg = edge group (0..1), sc = 16B col slice (0..7).
// 8 edges/iter, 8 gathers in flight/lane; next-iter meta prefetched BEFORE
// the FMA block so its L2 latency overlaps the gather waits. (round-12 loop,
// A/B-verified; round-16's 32-lane variant regressed — this is the optimum.)
__global__ __launch_bounds__(256) void k_aggc(
    const ushort* __restrict__ xwc, const int* __restrict__ row_start,
    const uint2* __restrict__ meta, const int* __restrict__ perm,
    const float* __restrict__ dinv, const float* __restrict__ bias,
    const float* __restrict__ slope, ushort* __restrict__ z1,
    ushort* __restrict__ z2) {
  const int blk = blockIdx.x;
  const int ch = blk / CHB;        // chunk phase (x-ordered dispatch)
  const int rb = blk % CHB;
  const int tid = threadIdx.x;
  const int r = rb * RPB + (tid >> 4);
  const int l = tid & 15;
  const int eg = l >> 3;           // 0..1
  const int sc = l & 7;            // 0..7 (8 cols each)
  const ushort* xcs = xwc + (size_t)ch * CHSZ + sc * 8;  // col-slice base
  const uint2* mp = meta + eg * 2; // per-lane meta base

  f32x2 a1[4] = {{0.f, 0.f}, {0.f, 0.f}, {0.f, 0.f}, {0.f, 0.f}};
  f32x2 a2[4] = {{0.f, 0.f}, {0.f, 0.f}, {0.f, 0.f}, {0.f, 0.f}};
  int e = row_start[r];
  const int eEnd = row_start[r + 1];
  if (e < eEnd) {
    uint4 m0 = *reinterpret_cast<const uint4*>(mp + e);
    uint4 m1 = *reinterpret_cast<const uint4*>(mp + e + 4);
    while (e < eEnd) {
      uint4 vA1 = *reinterpret_cast<const uint4*>(xcs + ((m0.x & 0xFFFFu) << 6));
      uint4 vA2 = *reinterpret_cast<const uint4*>(xcs + ((m0.x >> 16) << 6));
      uint4 vB1 = *reinterpret_cast<const uint4*>(xcs + ((m0.z & 0xFFFFu) << 6));
      uint4 vB2 = *reinterpret_cast<const uint4*>(xcs + ((m0.z >> 16) << 6));
      uint4 vC1 = *reinterpret_cast<const uint4*>(xcs + ((m1.x & 0xFFFFu) << 6));
      uint4 vC2 = *reinterpret_cast<const uint4*>(xcs + ((m1.x >> 16) << 6));
      uint4 vD1 = *reinterpret_cast<const uint4*>(xcs + ((m1.z & 0xFFFFu) << 6));
      uint4 vD2 = *reinterpret_cast<const uint4*>(xcs + ((m1.z >> 16) << 6));
      const int en = e + 8;
      const int ep = (en < eEnd) ? en : e;
      uint4 m0n = *reinterpret_cast<const uint4*>(mp + ep);
      uint4 m1n = *reinterpret_cast<const uint4*>(mp + ep + 4);
      const float fA = __uint_as_float(m0.y), fB = __uint_as_float(m0.w);
      const float fC = __uint_as_float(m1.y), fD = __uint_as_float(m1.w);
      const f32x2 nA = {fA, fA}, nB = {fB, fB}, nC = {fC, fC}, nD = {fD, fD};
      fma8v(a1, vA1, nA); fma8v(a2, vA2, nA);
      fma8v(a1, vB1, nB); fma8v(a2, vB2, nB);
      fma8v(a1, vC1, nC); fma8v(a2, vC2, nC);
      fma8v(a1, vD1, nD); fma8v(a2, vD2, nD);
      m0 = m0n; m1 = m1n;
      e = en;
    }
  }
  // reduce the eg dimension (partner within the 16-lane row group)
#pragma unroll
  for (int j = 0; j < 4; ++j) {
    a1[j].x += __shfl_xor(a1[j].x, 8);
    a1[j].y += __shfl_xor(a1[j].y, 8);
    a2[j].x += __shfl_xor(a2[j].x, 8);
    a2[j].y += __shfl_xor(a2[j].y, 8);
  }
  if (eg == 0) {
    const float di = dinv[r];
    const float d2 = di * di;
    const f32x2 nd = {d2, d2};
    const int pr = perm[r];
    uint4 s1 = *reinterpret_cast<const uint4*>(xcs + ((unsigned)r << 6));
    uint4 s2 = *reinterpret_cast<const uint4*>(xcs + ((unsigned)pr << 6));
    fma8v(a1, s1, nd); fma8v(a2, s2, nd);
    const float* bp = bias + ch * CCOLS + sc * 8;
    float4 b0 = *reinterpret_cast<const float4*>(bp);
    float4 b1 = *reinterpret_cast<const float4*>(bp + 4);
    a1[0] += (f32x2){b0.x, b0.y}; a1[1] += (f32x2){b0.z, b0.w};
    a1[2] += (f32x2){b1.x, b1.y}; a1[3] += (f32x2){b1.z, b1.w};
    a2[0] += (f32x2){b0.x, b0.y}; a2[1] += (f32x2){b0.z, b0.w};
    a2[2] += (f32x2){b1.x, b1.y}; a2[3] += (f32x2){b1.z, b1.w};
    const float a0 = slope[0];
#pragma unroll
    for (int j = 0; j < 4; ++j) {
      a1[j].x = a1[j].x >= 0.f ? a1[j].x : a0 * a1[j].x;
      a1[j].y = a1[j].y >= 0.f ? a1[j].y : a0 * a1[j].y;
      a2[j].x = a2[j].x >= 0.f ? a2[j].x : a0 * a2[j].x;
      a2[j].y = a2[j].y >= 0.f ? a2[j].y : a0 * a2[j].y;
    }
    uint4 p1, p2;
    p1.x = f2bf(a1[0].x) | (f2bf(a1[0].y) << 16);
    p1.y = f2bf(a1[1].x) | (f2bf(a1[1].y) << 16);
    p1.z = f2bf(a1[2].x) | (f2bf(a1[2].y) << 16);
    p1.w = f2bf(a1[3].x) | (f2bf(a1[3].y) << 16);
    p2.x = f2bf(a2[0].x) | (f2bf(a2[0].y) << 16);
    p2.y = f2bf(a2[1].x) | (f2bf(a2[1].y) << 16);
    p2.z = f2bf(a2[2].x) | (f2bf(a2[2].y) << 16);
    p2.w = f2bf(a2[3].x) | (f2bf(a2[3].y) << 16);
    const size_t o = (size_t)r * DIM + ch * CCOLS + sc * 8;  // z row-major
    *reinterpret_cast<uint4*>(z1 + o) = p1;
    *reinterpret_cast<uint4*>(z2 + o) = p2;
  }
}

// ---------------- column sums (2-stage, no atomics, CSB=512) ----------------

__global__ __launch_bounds__(256) void k_colsum(const ushort* __restrict__ z1,
                                                float* __restrict__ partial) {
  __shared__ float red[8 * 256];
  const int t = threadIdx.x;
  const int c8 = t & 31;       // col block of 8
  const int g = t >> 5;        // row group 0..7
  float s[8] = {0.f, 0.f, 0.f, 0.f, 0.f, 0.f, 0.f, 0.f};
  for (int r = blockIdx.x * 8 + g; r < N_NODES; r += 8 * CSB) {
    uint4 v = *reinterpret_cast<const uint4*>(z1 + (size_t)r * DIM + c8 * 8);
    s[0] += bf_lo(v.x); s[1] += bf_hi(v.x);
    s[2] += bf_lo(v.y); s[3] += bf_hi(v.y);
    s[4] += bf_lo(v.z); s[5] += bf_hi(v.z);
    s[6] += bf_lo(v.w); s[7] += bf_hi(v.w);
  }
#pragma unroll
  for (int j = 0; j < 8; ++j) red[g * 256 + c8 * 8 + j] = s[j];
  __syncthreads();
  float tot = 0.f;
#pragma unroll
  for (int g2 = 0; g2 < 8; ++g2) tot += red[g2 * 256 + t];
  partial[blockIdx.x * 256 + t] = tot;  // coalesced, no atomics
}

// reduce partials + sigmoid + wsum = disc_W @ summary, one block
__global__ __launch_bounds__(256) void k_wsum(const float* __restrict__ partial,
                                              const float* __restrict__ disc_W,
                                              float* __restrict__ wsum) {
  __shared__ float s[DIM];
  const int t = threadIdx.x;
  float a0 = 0.f, a1 = 0.f, a2 = 0.f, a3 = 0.f;
  for (int b = 0; b < CSB; b += 4) {
    a0 += partial[(b + 0) * 256 + t];
    a1 += partial[(b + 1) * 256 + t];
    a2 += partial[(b + 2) * 256 + t];
    a3 += partial[(b + 3) * 256 + t];
  }
  float m = (a0 + a1 + a2 + a3) * (1.0f / (float)N_NODES);
  s[t] = 1.0f / (1.0f + expf(-m));
  __syncthreads();
  float acc = 0.f;
  for (int j = 0; j < DIM; j += 4) {
    float4 w4 = *reinterpret_cast<const float4*>(&disc_W[t * DIM + j]);
    acc += w4.x * s[j] + w4.y * s[j + 1] + w4.z * s[j + 2] + w4.w * s[j + 3];
  }
  wsum[t] = acc;
}

// ---------------- pos = z1 @ wsum, neg = z2 @ wsum (wave per row) ----------------

__global__ __launch_bounds__(256) void k_posneg(const ushort* __restrict__ z1,
                                                const ushort* __restrict__ z2,
                                                const float* __restrict__ wsum,
                                                float* __restrict__ pos,
                                                float* __restrict__ neg) {
  const int wid = (blockIdx.x * blockDim.x + threadIdx.x) >> 6;
  const int lane = threadIdx.x & 63;
  if (wid >= N_NODES) return;
  uint2 v1 = *reinterpret_cast<const uint2*>(z1 + (size_t)wid * DIM + lane * 4);
  uint2 v2 = *reinterpret_cast<const uint2*>(z2 + (size_t)wid * DIM + lane * 4);
  float4 w4 = *reinterpret_cast<const float4*>(&wsum[lane * 4]);
  float dp = bf_lo(v1.x) * w4.x + bf_hi(v1.x) * w4.y + bf_lo(v1.y) * w4.z + bf_hi(v1.y) * w4.w;
  float dn = bf_lo(v2.x) * w4.x + bf_hi(v2.x) * w4.y + bf_lo(v2.y) * w4.z + bf_hi(v2.y) * w4.w;
#pragma unroll
  for (int off = 32; off > 0; off >>= 1) {
    dp += __shfl_down(dp, off);
    dn += __shfl_down(dn, off);
  }
  if (lane == 0) { pos[wid] = dp; neg[wid] = dn; }
}

// ---------------- launch ----------------

extern "C" void kernel_launch(void* const* d_in, const int* in_sizes, int n_in,
                              void* d_out, int out_size, void* d_ws, size_t ws_size,
                              hipStream_t stream) {
  const float* x      = (const float*)d_in[0];
  const float* W      = (const float*)d_in[1];
  const float* b      = (const float*)d_in[2];
  const float* a      = (const float*)d_in[3];
  const float* disc_W = (const float*)d_in[4];
  const int*   eidx   = (const int*)d_in[5];
  const int*   perm   = (const int*)d_in[6];
  const int* src = eidx;
  const int* dst = eidx + N_EDGES;

  constexpr size_t SZ_BFM  = (size_t)N_NODES * DIM * 2;  // 25.6 MB
  constexpr size_t SZ_META = (size_t)MAXE * 8;           // 9.6 MB
  constexpr size_t OFF_XWC = 0;
  constexpr size_t OFF_Z1  = OFF_XWC + SZ_BFM;
  constexpr size_t OFF_Z2  = OFF_Z1 + SZ_BFM;
  constexpr size_t OFF_WT  = OFF_Z2 + SZ_BFM;
  constexpr size_t OFF_DEG = OFF_WT + 131072;
  constexpr size_t OFF_DNV = OFF_DEG + 200192;
  constexpr size_t OFF_RS  = OFF_DNV + 200192;  // row_start: N+1 ints
  constexpr size_t OFF_CUR = OFF_RS + 200448;
  constexpr size_t OFF_MT  = OFF_CUR + 200192;
  constexpr size_t OFF_WSM = OFF_MT + SZ_META;
  constexpr size_t OFF_BS  = OFF_WSM + 1024;
  constexpr size_t OFF_BO  = OFF_BS + 1024;
  constexpr size_t OFF_PT  = OFF_BO + 1024;
  constexpr size_t NEED    = OFF_PT + (size_t)CSB * 256 * 4;
  if (ws_size < NEED) return;

  char* ws = (char*)d_ws;
  ushort* xwc    = (ushort*)(ws + OFF_XWC);
  ushort* z1     = (ushort*)(ws + OFF_Z1);
  ushort* z2     = (ushort*)(ws + OFF_Z2);
  ushort* Wt     = (ushort*)(ws + OFF_WT);
  int*    deg    = (int*)(ws + OFF_DEG);
  float*  dinv   = (float*)(ws + OFF_DNV);
  int*    rowst  = (int*)(ws + OFF_RS);
  int*    cursor = (int*)(ws + OFF_CUR);
  uint2*  meta   = (uint2*)(ws + OFF_MT);
  float*  wsum   = (float*)(ws + OFF_WSM);
  int*    bsum   = (int*)(ws + OFF_BS);
  int*    boff   = (int*)(ws + OFF_BO);
  float*  partial= (float*)(ws + OFF_PT);

  float* pos = (float*)d_out;
  float* neg = pos + N_NODES;

  hipMemsetAsync(deg, 0, N_NODES * sizeof(int), stream);
  hipMemsetAsync(meta, 0, SZ_META, stream);  // pad slots -> {src 0, psrc 0, norm 0}

  k_deg<<<(N_EDGES + 255) / 256, 256, 0, stream>>>(dst, deg);
  k_bsum<<<NB, 256, 0, stream>>>(deg, dinv, bsum);
  k_bscan<<<1, 256, 0, stream>>>(bsum, boff, rowst);
  k_rowstart<<<NB, 256, 0, stream>>>(deg, boff, rowst, cursor);
  k_scatter<<<(N_EDGES + 255) / 256, 256, 0, stream>>>(src, dst, perm, dinv,
                                                       cursor, meta);

  k_prep<<<DIM, DIM, 0, stream>>>(W, Wt);
  k_gemm<<<(N_NODES + 127) / 128, 512, 0, stream>>>(x, Wt, xwc);

  // fused dual aggregation: 4 chunk phases x 3125 row-blocks (x-ordered)
  k_aggc<<<NCH * CHB, 256, 0, stream>>>(xwc, rowst, meta, perm, dinv, b, a, z1, z2);

  k_colsum<<<CSB, 256, 0, stream>>>(z1, partial);
  k_wsum<<<1, 256, 0, stream>>>(partial, disc_W, wsum);
  k_posneg<<<(N_NODES * 64 + 255) / 256, 256, 0, stream>>>(z1, z2, wsum, pos, neg);
}